// Round 2
// baseline (246.727 us; speedup 1.0000x reference)
//
#include <hip/hip_runtime.h>
#include <hip/hip_bf16.h>
#include <math.h>

typedef __attribute__((ext_vector_type(8))) __bf16 bf16x8;
typedef __attribute__((ext_vector_type(4))) float f32x4;

// Problem constants
#define NN 4096
#define KN 48
#define HD 128
#define ED 384

// ws layout (bf16 element offsets). Weights are packed in MFMA B-fragment
// order: pack[ks][n][lane][j] = W[k = ks*32 + (lane>>4)*8 + j][col = n*16 + (lane&15)]
// so a wave's B-frag load is one coalesced 1KB global_load (lane*16B).
#define OFF_HVB    0         // h_V as bf16 [4096][128]
#define OFF_W1P    524288    // W1 pack [16][8][64][8]
#define OFF_W2P    589824    // W2 pack [4][8][64][8]
#define OFF_W3P    606208    // W3 pack [4][8][64][8]
#define OFF_WINP   622592    // Win pack [4][32][64][8]
#define OFF_WOUTP  688128    // Wout pack [16][8][64][8]
#define NPREP      753664
#define OFF_DH_BYTES 1507328 // f32 dh [4096][128] after the bf16 region

__device__ __forceinline__ float gelu_f(float x) {
  return 0.5f * x * (1.0f + erff(x * 0.70710678118654752440f));
}

// ---------------- prep: bf16 casts + weight fragment-packing ----------------
__global__ __launch_bounds__(256) void prep_kernel(
    const float* __restrict__ hV, const float* __restrict__ W1,
    const float* __restrict__ W2, const float* __restrict__ W3,
    const float* __restrict__ Wi, const float* __restrict__ Wo,
    __bf16* __restrict__ wsb)
{
  int i = blockIdx.x * 256 + threadIdx.x;
  float v;
  if (i < 524288) {
    v = hV[i];
  } else if (i < 589824) {            // W1 pack: [16][8][64][8], src W1[512][128]
    int j = i - 524288;
    int jj = j & 7, ln = (j >> 3) & 63, n = (j >> 9) & 7, ks = j >> 12;
    int k = ks * 32 + (ln >> 4) * 8 + jj, h = n * 16 + (ln & 15);
    v = W1[k * 128 + h];
  } else if (i < 606208) {            // W2 pack: [4][8][64][8], src W2[128][128]
    int j = i - 589824;
    int jj = j & 7, ln = (j >> 3) & 63, n = (j >> 9) & 7, ks = j >> 12;
    int k = ks * 32 + (ln >> 4) * 8 + jj, g = n * 16 + (ln & 15);
    v = W2[k * 128 + g];
  } else if (i < 622592) {            // W3 pack: [4][8][64][8], src W3[128][128]
    int j = i - 606208;
    int jj = j & 7, ln = (j >> 3) & 63, n = (j >> 9) & 7, ks = j >> 12;
    int k = ks * 32 + (ln >> 4) * 8 + jj, h = n * 16 + (ln & 15);
    v = W3[k * 128 + h];
  } else if (i < 688128) {            // Win pack: [4][32][64][8], src Win[128][512]
    int j = i - 622592;
    int jj = j & 7, ln = (j >> 3) & 63, n = (j >> 9) & 31, ks = j >> 14;
    int k = ks * 32 + (ln >> 4) * 8 + jj, o = n * 16 + (ln & 15);
    v = Wi[k * 512 + o];
  } else {                            // Wout pack: [16][8][64][8], src Wout[512][128]
    int j = i - 688128;
    int jj = j & 7, ln = (j >> 3) & 63, n = (j >> 9) & 7, ks = j >> 12;
    int k = ks * 32 + (ln >> 4) * 8 + jj, h = n * 16 + (ln & 15);
    v = Wo[k * 128 + h];
  }
  wsb[i] = (__bf16)v;
}

// ---------------- kernel 1: fused edge MLP + masked K-reduce ----------------
// block = 4 waves, wave w owns node blockIdx*4+w (48 edge rows). NO barriers:
// A-frags for GEMM1 load straight from HBM (each element used by exactly one
// lane), B-frags from packed weights (L2), layers 2/3 use a wave-private LDS
// transpose buffer.
__global__ __launch_bounds__(256, 2) void edge_mlp_kernel(
    const float* __restrict__ hE, const float* __restrict__ mask_att,
    const __bf16* __restrict__ wsb,
    const float* __restrict__ b1, const float* __restrict__ b2,
    const float* __restrict__ b3, float* __restrict__ dh)
{
  __shared__ char lds[49152];

  const int tid = threadIdx.x;
  const int w = tid >> 6, lane = tid & 63;
  const int lo = lane & 15, hi = lane >> 4;
  const int node = blockIdx.x * 4 + w;
  char* X = lds + w * 12288;   // wave-private [48 rows][256B], XOR-swizzled

  const __bf16* hVb = wsb + OFF_HVB;
  const __bf16* W1p = wsb + OFF_W1P;
  const __bf16* W2p = wsb + OFF_W2P;
  const __bf16* W3p = wsb + OFF_W3P;

  f32x4 acc[3][8];
#pragma unroll
  for (int m = 0; m < 3; m++)
#pragma unroll
    for (int n = 0; n < 8; n++) {
      acc[m][n][0] = 0.f; acc[m][n][1] = 0.f; acc[m][n][2] = 0.f; acc[m][n][3] = 0.f;
    }

  // ---- GEMM1 part 1: h_V broadcast columns (k-steps 0..3) ----
  // All 48 rows of this node share the same h_V row -> one a-frag for all m.
#pragma unroll
  for (int ks = 0; ks < 4; ++ks) {
    bf16x8 a = *(const bf16x8*)(hVb + node * 128 + ks * 32 + hi * 8);
#pragma unroll
    for (int n = 0; n < 8; n++) {
      bf16x8 b = *(const bf16x8*)(W1p + ((ks * 8 + n) << 9) + lane * 8);
      acc[0][n] = __builtin_amdgcn_mfma_f32_16x16x32_bf16(a, b, acc[0][n], 0, 0, 0);
      acc[1][n] = __builtin_amdgcn_mfma_f32_16x16x32_bf16(a, b, acc[1][n], 0, 0, 0);
      acc[2][n] = __builtin_amdgcn_mfma_f32_16x16x32_bf16(a, b, acc[2][n], 0, 0, 0);
    }
  }

  // ---- GEMM1 part 2: h_E columns (k-steps 4..15), direct-from-HBM A-frags,
  //      1-step software prefetch (fully unrolled -> all regs) ----
  const float* eb[3];
#pragma unroll
  for (int m = 0; m < 3; m++)
    eb[m] = hE + (size_t)(node * 48 + m * 16 + lo) * 384 + hi * 8;

  float4 c0[3], c1[3], p0[3], p1[3];
#pragma unroll
  for (int m = 0; m < 3; m++) {
    c0[m] = *(const float4*)(eb[m]);
    c1[m] = *(const float4*)(eb[m] + 4);
  }
#pragma unroll
  for (int ks = 4; ks < 16; ++ks) {
    if (ks < 15) {
#pragma unroll
      for (int m = 0; m < 3; m++) {
        p0[m] = *(const float4*)(eb[m] + (ks - 3) * 32);
        p1[m] = *(const float4*)(eb[m] + (ks - 3) * 32 + 4);
      }
    }
    bf16x8 a[3];
#pragma unroll
    for (int m = 0; m < 3; m++) {
      a[m][0] = (__bf16)c0[m].x; a[m][1] = (__bf16)c0[m].y;
      a[m][2] = (__bf16)c0[m].z; a[m][3] = (__bf16)c0[m].w;
      a[m][4] = (__bf16)c1[m].x; a[m][5] = (__bf16)c1[m].y;
      a[m][6] = (__bf16)c1[m].z; a[m][7] = (__bf16)c1[m].w;
    }
#pragma unroll
    for (int n = 0; n < 8; n++) {
      bf16x8 b = *(const bf16x8*)(W1p + ((ks * 8 + n) << 9) + lane * 8);
      acc[0][n] = __builtin_amdgcn_mfma_f32_16x16x32_bf16(a[0], b, acc[0][n], 0, 0, 0);
      acc[1][n] = __builtin_amdgcn_mfma_f32_16x16x32_bf16(a[1], b, acc[1][n], 0, 0, 0);
      acc[2][n] = __builtin_amdgcn_mfma_f32_16x16x32_bf16(a[2], b, acc[2][n], 0, 0, 0);
    }
#pragma unroll
    for (int m = 0; m < 3; m++) { c0[m] = p0[m]; c1[m] = p1[m]; }
  }

  // ---- layers 2 and 3: wave-private [48,128] @ W[128,128], no barriers ----
  const float* bvec[2] = { b1, b2 };
  const __bf16* Wps[2] = { W2p, W3p };
#pragma unroll
  for (int layer = 0; layer < 2; ++layer) {
    // gelu(acc + b) -> X (bf16, swizzled); reset acc
#pragma unroll
    for (int n = 0; n < 8; n++) {
      float bc = bvec[layer][n * 16 + lo];
      int colb = (n * 16 + lo) * 2;
#pragma unroll
      for (int m = 0; m < 3; m++)
#pragma unroll
        for (int i = 0; i < 4; i++) {
          int row = m * 16 + hi * 4 + i;
          float g = gelu_f(acc[m][n][i] + bc);
          *(__bf16*)(X + row * 256 + (colb ^ ((row & 7) << 4))) = (__bf16)g;
          acc[m][n][i] = 0.f;
        }
    }
    const __bf16* Wp = Wps[layer];
#pragma unroll
    for (int ks = 0; ks < 4; ++ks) {
      bf16x8 a[3];
#pragma unroll
      for (int m = 0; m < 3; m++) {
        int row = m * 16 + lo;
        a[m] = *(const bf16x8*)(X + row * 256 + ((ks * 64 + hi * 16) ^ ((row & 7) << 4)));
      }
#pragma unroll
      for (int n = 0; n < 8; n++) {
        bf16x8 b = *(const bf16x8*)(Wp + ((ks * 8 + n) << 9) + lane * 8);
        acc[0][n] = __builtin_amdgcn_mfma_f32_16x16x32_bf16(a[0], b, acc[0][n], 0, 0, 0);
        acc[1][n] = __builtin_amdgcn_mfma_f32_16x16x32_bf16(a[1], b, acc[1][n], 0, 0, 0);
        acc[2][n] = __builtin_amdgcn_mfma_f32_16x16x32_bf16(a[2], b, acc[2][n], 0, 0, 0);
      }
    }
  }

  // ---- epilogue: + b3, * mask_attend, sum over 48 rows, /SCALE ----
  float msk[12];
#pragma unroll
  for (int m = 0; m < 3; m++)
#pragma unroll
    for (int i = 0; i < 4; i++)
      msk[m * 4 + i] = mask_att[node * 48 + m * 16 + hi * 4 + i];

#pragma unroll
  for (int n = 0; n < 8; n++) {
    float bc = b3[n * 16 + lo];
    float s = 0.f;
#pragma unroll
    for (int m = 0; m < 3; m++)
#pragma unroll
      for (int i = 0; i < 4; i++)
        s += (acc[m][n][i] + bc) * msk[m * 4 + i];
    s += __shfl_xor(s, 16);
    s += __shfl_xor(s, 32);
    if (hi == 0)
      dh[node * 128 + n * 16 + lo] = s * (1.0f / 30.0f);
  }
}

// ---------------- kernel 2: LN1 + FFN + LN2 + mask ----------------
// block = 16 nodes, 4 waves
__global__ __launch_bounds__(256, 2) void node_ffn_kernel(
    const float* __restrict__ hV, const float* __restrict__ maskV,
    const __bf16* __restrict__ wsb, const float* __restrict__ dh,
    const float* __restrict__ Winb, const float* __restrict__ Woutb,
    const float* __restrict__ ns1, const float* __restrict__ no1,
    const float* __restrict__ ns2, const float* __restrict__ no2,
    float* __restrict__ out)
{
  __shared__ char lds[36864];
  char*  xA  = lds;                    // [16][256B] bf16, swizzled
  float* hvn = (float*)(lds + 4096);   // [16][128] f32 (h_Vn after LN1)
  char*  A2  = lds + 12288;            // [16][1024B] bf16, swizzled
  float* red = (float*)(lds + 28672);  // [16][128] f32 (FFN output)

  const __bf16* Winp  = wsb + OFF_WINP;
  const __bf16* Woutp = wsb + OFF_WOUTP;

  const int tid = threadIdx.x;
  const int w = tid >> 6, lane = tid & 63;
  const int lo = lane & 15, hi = lane >> 4;
  const int n0 = blockIdx.x * 16;

  const int row = tid >> 4;   // 0..15 (node within block)
  const int sg  = tid & 15;   // 0..15 (8-feature segment)
  const int node = n0 + row;

  // Phase 0: x = h_V + dh, LN1 -> hvn (f32) and xA (bf16)
  {
    const float* pv = hV + node * 128 + sg * 8;
    const float* pd = dh + node * 128 + sg * 8;
    float4 a0 = *(const float4*)pv;
    float4 a1 = *(const float4*)(pv + 4);
    float4 d0 = *(const float4*)pd;
    float4 d1 = *(const float4*)(pd + 4);
    float x[8] = { a0.x + d0.x, a0.y + d0.y, a0.z + d0.z, a0.w + d0.w,
                   a1.x + d1.x, a1.y + d1.y, a1.z + d1.z, a1.w + d1.w };
    float s = 0.f, sq = 0.f;
#pragma unroll
    for (int j = 0; j < 8; j++) { s += x[j]; sq += x[j] * x[j]; }
#pragma unroll
    for (int off = 8; off >= 1; off >>= 1) { s += __shfl_xor(s, off); sq += __shfl_xor(sq, off); }
    float mean = s * (1.f / 128.f);
    float var  = sq * (1.f / 128.f) - mean * mean;
    float rs = rsqrtf(var + 1e-5f);
    bf16x8 vb;
    float yv[8];
#pragma unroll
    for (int j = 0; j < 8; j++) {
      int col = sg * 8 + j;
      float y = (x[j] - mean) * rs * ns1[col] + no1[col];
      yv[j] = y; vb[j] = (__bf16)y;
    }
    *(float4*)(hvn + row * 128 + sg * 8)     = make_float4(yv[0], yv[1], yv[2], yv[3]);
    *(float4*)(hvn + row * 128 + sg * 8 + 4) = make_float4(yv[4], yv[5], yv[6], yv[7]);
    *(bf16x8*)(xA + row * 256 + ((sg * 16) ^ ((row & 7) << 4))) = vb;
  }
  __syncthreads();

  // Phase 1: [16,128] @ Win -> [16,512]; wave w owns output cols w*128..+127
  f32x4 acc[8];
#pragma unroll
  for (int n = 0; n < 8; n++) { acc[n][0] = 0.f; acc[n][1] = 0.f; acc[n][2] = 0.f; acc[n][3] = 0.f; }
#pragma unroll
  for (int ks = 0; ks < 4; ks++) {
    const int kb = (ks * 32 + hi * 8) * 2;
    bf16x8 a = *(const bf16x8*)(xA + lo * 256 + (kb ^ ((lo & 7) << 4)));
#pragma unroll
    for (int n = 0; n < 8; n++) {
      int ng = w * 8 + n;
      bf16x8 b = *(const bf16x8*)(Winp + ((ks * 32 + ng) << 9) + lane * 8);
      acc[n] = __builtin_amdgcn_mfma_f32_16x16x32_bf16(a, b, acc[n], 0, 0, 0);
    }
  }
  // Phase 2: gelu -> A2 [16][512] bf16 (stride 1024B, swizzled)
#pragma unroll
  for (int n = 0; n < 8; n++) {
    int col = w * 128 + n * 16 + lo;
    float bc = Winb[col];
#pragma unroll
    for (int i = 0; i < 4; i++) {
      int r2 = hi * 4 + i;
      float g = gelu_f(acc[n][i] + bc);
      *(__bf16*)(A2 + r2 * 1024 + ((col * 2) ^ ((r2 & 7) << 4))) = (__bf16)g;
    }
  }
  __syncthreads();

  // Phase 3: [16,512] @ Wout -> [16,128]; wave w owns output cols w*32..+31
  f32x4 acc2[2];
  acc2[0][0] = 0.f; acc2[0][1] = 0.f; acc2[0][2] = 0.f; acc2[0][3] = 0.f;
  acc2[1][0] = 0.f; acc2[1][1] = 0.f; acc2[1][2] = 0.f; acc2[1][3] = 0.f;
#pragma unroll
  for (int ks = 0; ks < 16; ks++) {
    const int kb = (ks * 32 + hi * 8) * 2;
    bf16x8 a = *(const bf16x8*)(A2 + lo * 1024 + (kb ^ ((lo & 7) << 4)));
#pragma unroll
    for (int n = 0; n < 2; n++) {
      int ng = w * 2 + n;
      bf16x8 b = *(const bf16x8*)(Woutp + ((ks * 8 + ng) << 9) + lane * 8);
      acc2[n] = __builtin_amdgcn_mfma_f32_16x16x32_bf16(a, b, acc2[n], 0, 0, 0);
    }
  }
  // Phase 4: + bias -> red
#pragma unroll
  for (int n = 0; n < 2; n++) {
    int col = w * 32 + n * 16 + lo;
    float bc = Woutb[col];
#pragma unroll
    for (int i = 0; i < 4; i++) {
      int r2 = hi * 4 + i;
      red[r2 * 128 + col] = acc2[n][i] + bc;
    }
  }
  __syncthreads();

  // Phase 5: LN2(hvn + red) * mask_V -> out
  {
    const float* ph = hvn + row * 128 + sg * 8;
    const float* pr = red + row * 128 + sg * 8;
    float4 h0 = *(const float4*)ph;
    float4 h1 = *(const float4*)(ph + 4);
    float4 r0 = *(const float4*)pr;
    float4 r1 = *(const float4*)(pr + 4);
    float x[8] = { h0.x + r0.x, h0.y + r0.y, h0.z + r0.z, h0.w + r0.w,
                   h1.x + r1.x, h1.y + r1.y, h1.z + r1.z, h1.w + r1.w };
    float s = 0.f, sq = 0.f;
#pragma unroll
    for (int j = 0; j < 8; j++) { s += x[j]; sq += x[j] * x[j]; }
#pragma unroll
    for (int off = 8; off >= 1; off >>= 1) { s += __shfl_xor(s, off); sq += __shfl_xor(sq, off); }
    float mean = s * (1.f / 128.f);
    float var  = sq * (1.f / 128.f) - mean * mean;
    float rs = rsqrtf(var + 1e-5f);
    float mv = maskV[node];
    float o[8];
#pragma unroll
    for (int j = 0; j < 8; j++) {
      int col = sg * 8 + j;
      o[j] = mv * ((x[j] - mean) * rs * ns2[col] + no2[col]);
    }
    *(float4*)(out + node * 128 + sg * 8)     = make_float4(o[0], o[1], o[2], o[3]);
    *(float4*)(out + node * 128 + sg * 8 + 4) = make_float4(o[4], o[5], o[6], o[7]);
  }
}

extern "C" void kernel_launch(void* const* d_in, const int* in_sizes, int n_in,
                              void* d_out, int out_size, void* d_ws, size_t ws_size,
                              hipStream_t stream)
{
  (void)in_sizes; (void)n_in; (void)out_size; (void)ws_size;
  const float* hV   = (const float*)d_in[0];
  const float* hE   = (const float*)d_in[1];
  const float* mV   = (const float*)d_in[2];
  const float* mAtt = (const float*)d_in[3];
  const float* W1   = (const float*)d_in[4];
  const float* b1   = (const float*)d_in[5];
  const float* W2   = (const float*)d_in[6];
  const float* b2   = (const float*)d_in[7];
  const float* W3   = (const float*)d_in[8];
  const float* b3   = (const float*)d_in[9];
  const float* Win  = (const float*)d_in[10];
  const float* binb = (const float*)d_in[11];
  const float* Wout = (const float*)d_in[12];
  const float* bout = (const float*)d_in[13];
  const float* ns1  = (const float*)d_in[14];
  const float* no1  = (const float*)d_in[15];
  const float* ns2  = (const float*)d_in[16];
  const float* no2  = (const float*)d_in[17];

  __bf16* wsb = (__bf16*)d_ws;
  float* dh   = (float*)((char*)d_ws + OFF_DH_BYTES);
  float* out  = (float*)d_out;

  prep_kernel<<<NPREP / 256, 256, 0, stream>>>(hV, W1, W2, W3, Win, Wout, wsb);
  edge_mlp_kernel<<<1024, 256, 0, stream>>>(hE, mAtt, wsb, b1, b2, b3, dh);
  node_ffn_kernel<<<256, 256, 0, stream>>>(hV, mV, wsb, dh, binb, bout,
                                           ns1, no1, ns2, no2, out);
}

// Round 3
// 188.822 us; speedup vs baseline: 1.3067x; 1.3067x over previous
//
#include <hip/hip_runtime.h>
#include <hip/hip_bf16.h>
#include <math.h>

typedef __attribute__((ext_vector_type(8))) __bf16 bf16x8;
typedef __attribute__((ext_vector_type(4))) float f32x4;

// Problem constants
#define NN 4096
#define KN 48
#define HD 128
#define ED 384

// ws layout (bf16 element offsets). Weights packed in MFMA B-fragment order:
// pack[ks][n][lane][j] = W[k = ks*32 + (lane>>4)*8 + j][col = n*16 + (lane&15)]
#define OFF_HVB    0         // h_V as bf16 [4096][128]
#define OFF_W1P    524288    // W1 pack [16][8][64][8]
#define OFF_W2P    589824    // W2 pack [4][8][64][8]
#define OFF_W3P    606208    // W3 pack [4][8][64][8]
#define OFF_WINP   622592    // Win pack [4][32][64][8]
#define OFF_WOUTP  688128    // Wout pack [16][8][64][8]
#define NPREP      753664
#define OFF_DH_BYTES 1507328 // f32 dh [4096][128] after the bf16 region

// Compact tanh-form gelu (~7 insts vs ~70 for ocml erff; abs err ~1e-4,
// final tolerance margin is 0.074 -> safe). x*sigma(2t) == 0.5x(1+tanh(t)).
__device__ __forceinline__ float gelu_f(float x) {
  float t = 1.5957691216f * x * (1.0f + 0.044715f * x * x);  // 2*0.79788456*(...)
  return __fdividef(x, 1.0f + __expf(-t));
}

__device__ __forceinline__ bf16x8 cvt8(float4 u, float4 v) {
  bf16x8 r;
  r[0] = (__bf16)u.x; r[1] = (__bf16)u.y; r[2] = (__bf16)u.z; r[3] = (__bf16)u.w;
  r[4] = (__bf16)v.x; r[5] = (__bf16)v.y; r[6] = (__bf16)v.z; r[7] = (__bf16)v.w;
  return r;
}

#define MFMA __builtin_amdgcn_mfma_f32_16x16x32_bf16

// ---------------- prep: bf16 casts + weight fragment-packing ----------------
__global__ __launch_bounds__(256) void prep_kernel(
    const float* __restrict__ hV, const float* __restrict__ W1,
    const float* __restrict__ W2, const float* __restrict__ W3,
    const float* __restrict__ Wi, const float* __restrict__ Wo,
    __bf16* __restrict__ wsb)
{
  int i = blockIdx.x * 256 + threadIdx.x;
  float v;
  if (i < 524288) {
    v = hV[i];
  } else if (i < 589824) {            // W1 pack, src W1[512][128]
    int j = i - 524288;
    int jj = j & 7, ln = (j >> 3) & 63, n = (j >> 9) & 7, ks = j >> 12;
    int k = ks * 32 + (ln >> 4) * 8 + jj, h = n * 16 + (ln & 15);
    v = W1[k * 128 + h];
  } else if (i < 606208) {            // W2 pack, src W2[128][128]
    int j = i - 589824;
    int jj = j & 7, ln = (j >> 3) & 63, n = (j >> 9) & 7, ks = j >> 12;
    int k = ks * 32 + (ln >> 4) * 8 + jj, g = n * 16 + (ln & 15);
    v = W2[k * 128 + g];
  } else if (i < 622592) {            // W3 pack, src W3[128][128]
    int j = i - 606208;
    int jj = j & 7, ln = (j >> 3) & 63, n = (j >> 9) & 7, ks = j >> 12;
    int k = ks * 32 + (ln >> 4) * 8 + jj, h = n * 16 + (ln & 15);
    v = W3[k * 128 + h];
  } else if (i < 688128) {            // Win pack, src Win[128][512]
    int j = i - 622592;
    int jj = j & 7, ln = (j >> 3) & 63, n = (j >> 9) & 31, ks = j >> 14;
    int k = ks * 32 + (ln >> 4) * 8 + jj, o = n * 16 + (ln & 15);
    v = Wi[k * 512 + o];
  } else {                            // Wout pack, src Wout[512][128]
    int j = i - 688128;
    int jj = j & 7, ln = (j >> 3) & 63, n = (j >> 9) & 7, ks = j >> 12;
    int k = ks * 32 + (ln >> 4) * 8 + jj, h = n * 16 + (ln & 15);
    v = Wo[k * 128 + h];
  }
  wsb[i] = (__bf16)v;
}

// ---------------- kernel 1: fused edge MLP + masked K-reduce ----------------
// 4 waves/block, wave w owns node blockIdx*4+w. Barrier-free; compact code
// (all outer loops rolled) so the kernel fits I$; B-frag loads issued BEFORE
// hE prefetch so vmcnt waits on B never drain the prefetch.
__global__ __launch_bounds__(256, 2) void edge_mlp_kernel(
    const float* __restrict__ hE, const float* __restrict__ mask_att,
    const __bf16* __restrict__ wsb,
    const float* __restrict__ b1, const float* __restrict__ b2,
    const float* __restrict__ b3, float* __restrict__ dh)
{
  __shared__ char lds[49152];

  const int tid = threadIdx.x;
  const int w = tid >> 6, lane = tid & 63;
  const int lo = lane & 15, hi = lane >> 4;
  const int node = blockIdx.x * 4 + w;
  char* X = lds + w * 12288;   // wave-private [48 rows][256B], XOR-swizzled

  const __bf16* hVb = wsb + OFF_HVB;
  const __bf16* W1p = wsb + OFF_W1P;

  f32x4 acc[3][8];
#pragma unroll
  for (int m = 0; m < 3; m++)
#pragma unroll
    for (int n = 0; n < 8; n++) {
      acc[m][n][0] = 0.f; acc[m][n][1] = 0.f; acc[m][n][2] = 0.f; acc[m][n][3] = 0.f;
    }

  // ---- GEMM1 part 1: h_V broadcast columns (k-steps 0..3), rolled ----
#pragma unroll 1
  for (int ks = 0; ks < 4; ++ks) {
    bf16x8 a = *(const bf16x8*)(hVb + node * 128 + ks * 32 + hi * 8);
#pragma unroll
    for (int n = 0; n < 8; n++) {
      bf16x8 b = *(const bf16x8*)(W1p + ((ks * 8 + n) << 9) + lane * 8);
      acc[0][n] = MFMA(a, b, acc[0][n], 0, 0, 0);
      acc[1][n] = MFMA(a, b, acc[1][n], 0, 0, 0);
      acc[2][n] = MFMA(a, b, acc[2][n], 0, 0, 0);
    }
  }

  // ---- GEMM1 part 2: h_E columns (k-steps 4..15), direct-from-HBM A-frags,
  //      ping-pong named buffers, prefetch distance = 2 k-steps ----
  const float* e0 = hE + (size_t)(node * 48 + lo) * 384 + hi * 8;
  const float* e1 = e0 + 16 * 384;
  const float* e2 = e0 + 32 * 384;

  float4 A0 = *(const float4*)(e0),      A1 = *(const float4*)(e0 + 4);
  float4 A2 = *(const float4*)(e1),      A3 = *(const float4*)(e1 + 4);
  float4 A4 = *(const float4*)(e2),      A5 = *(const float4*)(e2 + 4);
  float4 B0 = *(const float4*)(e0 + 32), B1 = *(const float4*)(e0 + 36);
  float4 B2 = *(const float4*)(e1 + 32), B3 = *(const float4*)(e1 + 36);
  float4 B4 = *(const float4*)(e2 + 32), B5 = *(const float4*)(e2 + 36);

#pragma unroll 1
  for (int kp = 0; kp < 6; ++kp) {
    const int ks0 = 4 + 2 * kp;
    // ---- slot 0 (even k-step): B-frag loads first ----
    {
      bf16x8 bb[8];
#pragma unroll
      for (int n = 0; n < 8; n++)
        bb[n] = *(const bf16x8*)(W1p + ((ks0 * 8 + n) << 9) + lane * 8);
      bf16x8 a0 = cvt8(A0, A1), a1 = cvt8(A2, A3), a2 = cvt8(A4, A5);
      const int of = (kp < 5 ? 2 * kp + 2 : 10) * 32;   // prefetch ks0+2 (clamped dummy on last)
      A0 = *(const float4*)(e0 + of); A1 = *(const float4*)(e0 + of + 4);
      A2 = *(const float4*)(e1 + of); A3 = *(const float4*)(e1 + of + 4);
      A4 = *(const float4*)(e2 + of); A5 = *(const float4*)(e2 + of + 4);
#pragma unroll
      for (int n = 0; n < 8; n++) {
        acc[0][n] = MFMA(a0, bb[n], acc[0][n], 0, 0, 0);
        acc[1][n] = MFMA(a1, bb[n], acc[1][n], 0, 0, 0);
        acc[2][n] = MFMA(a2, bb[n], acc[2][n], 0, 0, 0);
      }
    }
    // ---- slot 1 (odd k-step) ----
    {
      bf16x8 bb[8];
#pragma unroll
      for (int n = 0; n < 8; n++)
        bb[n] = *(const bf16x8*)(W1p + (((ks0 + 1) * 8 + n) << 9) + lane * 8);
      bf16x8 a0 = cvt8(B0, B1), a1 = cvt8(B2, B3), a2 = cvt8(B4, B5);
      const int of = (kp < 5 ? 2 * kp + 3 : 11) * 32;   // prefetch ks0+3
      B0 = *(const float4*)(e0 + of); B1 = *(const float4*)(e0 + of + 4);
      B2 = *(const float4*)(e1 + of); B3 = *(const float4*)(e1 + of + 4);
      B4 = *(const float4*)(e2 + of); B5 = *(const float4*)(e2 + of + 4);
#pragma unroll
      for (int n = 0; n < 8; n++) {
        acc[0][n] = MFMA(a0, bb[n], acc[0][n], 0, 0, 0);
        acc[1][n] = MFMA(a1, bb[n], acc[1][n], 0, 0, 0);
        acc[2][n] = MFMA(a2, bb[n], acc[2][n], 0, 0, 0);
      }
    }
  }

  // ---- layers 2 and 3: wave-private [48,128] @ W[128,128], rolled ----
#pragma unroll 1
  for (int layer = 0; layer < 2; ++layer) {
    const float*  bv = layer ? b2 : b1;
    const __bf16* Wp = wsb + (layer ? OFF_W3P : OFF_W2P);
    // gelu(acc + b) -> X (bf16, swizzled); reset acc
#pragma unroll
    for (int n = 0; n < 8; n++) {
      float bc = bv[n * 16 + lo];
      int colb = (n * 16 + lo) * 2;
#pragma unroll
      for (int m = 0; m < 3; m++)
#pragma unroll
        for (int i = 0; i < 4; i++) {
          int row = m * 16 + hi * 4 + i;
          float g = gelu_f(acc[m][n][i] + bc);
          *(__bf16*)(X + row * 256 + (colb ^ ((row & 7) << 4))) = (__bf16)g;
          acc[m][n][i] = 0.f;
        }
    }
#pragma unroll 1
    for (int ks = 0; ks < 4; ++ks) {
      const int kb = ks * 64 + hi * 16;
      const int sw = (lo & 7) << 4;
      bf16x8 a0 = *(const bf16x8*)(X + (lo)      * 256 + (kb ^ sw));
      bf16x8 a1 = *(const bf16x8*)(X + (16 + lo) * 256 + (kb ^ sw));
      bf16x8 a2 = *(const bf16x8*)(X + (32 + lo) * 256 + (kb ^ sw));
#pragma unroll
      for (int n = 0; n < 8; n++) {
        bf16x8 b = *(const bf16x8*)(Wp + ((ks * 8 + n) << 9) + lane * 8);
        acc[0][n] = MFMA(a0, b, acc[0][n], 0, 0, 0);
        acc[1][n] = MFMA(a1, b, acc[1][n], 0, 0, 0);
        acc[2][n] = MFMA(a2, b, acc[2][n], 0, 0, 0);
      }
    }
  }

  // ---- epilogue: + b3, * mask_attend, sum over 48 rows, /SCALE ----
  float msk[12];
#pragma unroll
  for (int m = 0; m < 3; m++)
#pragma unroll
    for (int i = 0; i < 4; i++)
      msk[m * 4 + i] = mask_att[node * 48 + m * 16 + hi * 4 + i];

#pragma unroll
  for (int n = 0; n < 8; n++) {
    float bc = b3[n * 16 + lo];
    float s = 0.f;
#pragma unroll
    for (int m = 0; m < 3; m++)
#pragma unroll
      for (int i = 0; i < 4; i++)
        s += (acc[m][n][i] + bc) * msk[m * 4 + i];
    s += __shfl_xor(s, 16);
    s += __shfl_xor(s, 32);
    if (hi == 0)
      dh[node * 128 + n * 16 + lo] = s * (1.0f / 30.0f);
  }
}

// ---------------- kernel 2: LN1 + FFN + LN2 + mask ----------------
// block = 16 nodes, 4 waves
__global__ __launch_bounds__(256, 2) void node_ffn_kernel(
    const float* __restrict__ hV, const float* __restrict__ maskV,
    const __bf16* __restrict__ wsb, const float* __restrict__ dh,
    const float* __restrict__ Winb, const float* __restrict__ Woutb,
    const float* __restrict__ ns1, const float* __restrict__ no1,
    const float* __restrict__ ns2, const float* __restrict__ no2,
    float* __restrict__ out)
{
  __shared__ char lds[36864];
  char*  xA  = lds;                    // [16][256B] bf16, swizzled
  float* hvn = (float*)(lds + 4096);   // [16][128] f32 (h_Vn after LN1)
  char*  A2  = lds + 12288;            // [16][1024B] bf16, swizzled
  float* red = (float*)(lds + 28672);  // [16][128] f32 (FFN output)

  const __bf16* Winp  = wsb + OFF_WINP;
  const __bf16* Woutp = wsb + OFF_WOUTP;

  const int tid = threadIdx.x;
  const int w = tid >> 6, lane = tid & 63;
  const int lo = lane & 15, hi = lane >> 4;
  const int n0 = blockIdx.x * 16;

  const int row = tid >> 4;   // 0..15 (node within block)
  const int sg  = tid & 15;   // 0..15 (8-feature segment)
  const int node = n0 + row;

  // Phase 0: x = h_V + dh, LN1 -> hvn (f32) and xA (bf16)
  {
    const float* pv = hV + node * 128 + sg * 8;
    const float* pd = dh + node * 128 + sg * 8;
    float4 a0 = *(const float4*)pv;
    float4 a1 = *(const float4*)(pv + 4);
    float4 d0 = *(const float4*)pd;
    float4 d1 = *(const float4*)(pd + 4);
    float x[8] = { a0.x + d0.x, a0.y + d0.y, a0.z + d0.z, a0.w + d0.w,
                   a1.x + d1.x, a1.y + d1.y, a1.z + d1.z, a1.w + d1.w };
    float s = 0.f, sq = 0.f;
#pragma unroll
    for (int j = 0; j < 8; j++) { s += x[j]; sq += x[j] * x[j]; }
#pragma unroll
    for (int off = 8; off >= 1; off >>= 1) { s += __shfl_xor(s, off); sq += __shfl_xor(sq, off); }
    float mean = s * (1.f / 128.f);
    float var  = sq * (1.f / 128.f) - mean * mean;
    float rs = rsqrtf(var + 1e-5f);
    bf16x8 vb;
    float yv[8];
#pragma unroll
    for (int j = 0; j < 8; j++) {
      int col = sg * 8 + j;
      float y = (x[j] - mean) * rs * ns1[col] + no1[col];
      yv[j] = y; vb[j] = (__bf16)y;
    }
    *(float4*)(hvn + row * 128 + sg * 8)     = make_float4(yv[0], yv[1], yv[2], yv[3]);
    *(float4*)(hvn + row * 128 + sg * 8 + 4) = make_float4(yv[4], yv[5], yv[6], yv[7]);
    *(bf16x8*)(xA + row * 256 + ((sg * 16) ^ ((row & 7) << 4))) = vb;
  }
  __syncthreads();

  // Phase 1: [16,128] @ Win -> [16,512]; wave w owns output cols w*128..+127
  f32x4 acc[8];
#pragma unroll
  for (int n = 0; n < 8; n++) { acc[n][0] = 0.f; acc[n][1] = 0.f; acc[n][2] = 0.f; acc[n][3] = 0.f; }
#pragma unroll
  for (int ks = 0; ks < 4; ks++) {
    const int kb = (ks * 32 + hi * 8) * 2;
    bf16x8 a = *(const bf16x8*)(xA + lo * 256 + (kb ^ ((lo & 7) << 4)));
#pragma unroll
    for (int n = 0; n < 8; n++) {
      int ng = w * 8 + n;
      bf16x8 b = *(const bf16x8*)(Winp + ((ks * 32 + ng) << 9) + lane * 8);
      acc[n] = MFMA(a, b, acc[n], 0, 0, 0);
    }
  }
  // Phase 2: gelu -> A2 [16][512] bf16 (stride 1024B, swizzled)
#pragma unroll
  for (int n = 0; n < 8; n++) {
    int col = w * 128 + n * 16 + lo;
    float bc = Winb[col];
#pragma unroll
    for (int i = 0; i < 4; i++) {
      int r2 = hi * 4 + i;
      float g = gelu_f(acc[n][i] + bc);
      *(__bf16*)(A2 + r2 * 1024 + ((col * 2) ^ ((r2 & 7) << 4))) = (__bf16)g;
    }
  }
  __syncthreads();

  // Phase 3: [16,512] @ Wout -> [16,128]; wave w owns output cols w*32..+31
  f32x4 acc2[2];
  acc2[0][0] = 0.f; acc2[0][1] = 0.f; acc2[0][2] = 0.f; acc2[0][3] = 0.f;
  acc2[1][0] = 0.f; acc2[1][1] = 0.f; acc2[1][2] = 0.f; acc2[1][3] = 0.f;
#pragma unroll
  for (int ks = 0; ks < 16; ks++) {
    const int kb = (ks * 32 + hi * 8) * 2;
    bf16x8 a = *(const bf16x8*)(A2 + lo * 1024 + (kb ^ ((lo & 7) << 4)));
#pragma unroll
    for (int n = 0; n < 2; n++) {
      int ng = w * 2 + n;
      bf16x8 b = *(const bf16x8*)(Woutp + ((ks * 8 + ng) << 9) + lane * 8);
      acc2[n] = MFMA(a, b, acc2[n], 0, 0, 0);
    }
  }
  // Phase 4: + bias -> red
#pragma unroll
  for (int n = 0; n < 2; n++) {
    int col = w * 32 + n * 16 + lo;
    float bc = Woutb[col];
#pragma unroll
    for (int i = 0; i < 4; i++) {
      int r2 = hi * 4 + i;
      red[r2 * 128 + col] = acc2[n][i] + bc;
    }
  }
  __syncthreads();

  // Phase 5: LN2(hvn + red) * mask_V -> out
  {
    const float* ph = hvn + row * 128 + sg * 8;
    const float* pr = red + row * 128 + sg * 8;
    float4 h0 = *(const float4*)ph;
    float4 h1 = *(const float4*)(ph + 4);
    float4 r0 = *(const float4*)pr;
    float4 r1 = *(const float4*)(pr + 4);
    float x[8] = { h0.x + r0.x, h0.y + r0.y, h0.z + r0.z, h0.w + r0.w,
                   h1.x + r1.x, h1.y + r1.y, h1.z + r1.z, h1.w + r1.w };
    float s = 0.f, sq = 0.f;
#pragma unroll
    for (int j = 0; j < 8; j++) { s += x[j]; sq += x[j] * x[j]; }
#pragma unroll
    for (int off = 8; off >= 1; off >>= 1) { s += __shfl_xor(s, off); sq += __shfl_xor(sq, off); }
    float mean = s * (1.f / 128.f);
    float var  = sq * (1.f / 128.f) - mean * mean;
    float rs = rsqrtf(var + 1e-5f);
    float mv = maskV[node];
    float o[8];
#pragma unroll
    for (int j = 0; j < 8; j++) {
      int col = sg * 8 + j;
      o[j] = mv * ((x[j] - mean) * rs * ns2[col] + no2[col]);
    }
    *(float4*)(out + node * 128 + sg * 8)     = make_float4(o[0], o[1], o[2], o[3]);
    *(float4*)(out + node * 128 + sg * 8 + 4) = make_float4(o[4], o[5], o[6], o[7]);
  }
}

extern "C" void kernel_launch(void* const* d_in, const int* in_sizes, int n_in,
                              void* d_out, int out_size, void* d_ws, size_t ws_size,
                              hipStream_t stream)
{
  (void)in_sizes; (void)n_in; (void)out_size; (void)ws_size;
  const float* hV   = (const float*)d_in[0];
  const float* hE   = (const float*)d_in[1];
  const float* mV   = (const float*)d_in[2];
  const float* mAtt = (const float*)d_in[3];
  const float* W1   = (const float*)d_in[4];
  const float* b1   = (const float*)d_in[5];
  const float* W2   = (const float*)d_in[6];
  const float* b2   = (const float*)d_in[7];
  const float* W3   = (const float*)d_in[8];
  const float* b3   = (const float*)d_in[9];
  const float* Win  = (const float*)d_in[10];
  const float* binb = (const float*)d_in[11];
  const float* Wout = (const float*)d_in[12];
  const float* bout = (const float*)d_in[13];
  const float* ns1  = (const float*)d_in[14];
  const float* no1  = (const float*)d_in[15];
  const float* ns2  = (const float*)d_in[16];
  const float* no2  = (const float*)d_in[17];

  __bf16* wsb = (__bf16*)d_ws;
  float* dh   = (float*)((char*)d_ws + OFF_DH_BYTES);
  float* out  = (float*)d_out;

  prep_kernel<<<NPREP / 256, 256, 0, stream>>>(hV, W1, W2, W3, Win, Wout, wsb);
  edge_mlp_kernel<<<1024, 256, 0, stream>>>(hE, mAtt, wsb, b1, b2, b3, dh);
  node_ffn_kernel<<<256, 256, 0, stream>>>(hV, mV, wsb, dh, binb, bout,
                                           ns1, no1, ns2, no2, out);
}

// Round 4
// 108.203 us; speedup vs baseline: 2.2802x; 1.7451x over previous
//
#include <hip/hip_runtime.h>
#include <hip/hip_bf16.h>
#include <math.h>

typedef __attribute__((ext_vector_type(8))) __bf16 bf16x8;
typedef __attribute__((ext_vector_type(4))) float f32x4;

// ws layout (bf16 element offsets). Weights packed in MFMA B-fragment order:
// pack[ks][n][lane][j] = W[k = ks*32 + (lane>>4)*8 + j][col = n*16 + (lane&15)]
#define OFF_HVB    0         // h_V as bf16 [4096][128]
#define OFF_W1P    524288    // W1 pack [16][8][64][8]
#define OFF_W2P    589824    // W2 pack [4][8][64][8]
#define OFF_W3P    606208    // W3 pack [4][8][64][8]
#define OFF_WINP   622592    // Win pack [4][32][64][8]
#define OFF_WOUTP  688128    // Wout pack [16][8][64][8]
#define NPREP      753664
#define OFF_DH_BYTES 1507328 // f32 dh [4096][128]

// Compact tanh-form gelu (abs err ~1e-4 << 0.074 margin)
__device__ __forceinline__ float gelu_f(float x) {
  float t = 1.5957691216f * x * (1.0f + 0.044715f * x * x);
  return __fdividef(x, 1.0f + __expf(-t));
}

__device__ __forceinline__ bf16x8 cvt8(float4 u, float4 v) {
  bf16x8 r;
  r[0] = (__bf16)u.x; r[1] = (__bf16)u.y; r[2] = (__bf16)u.z; r[3] = (__bf16)u.w;
  r[4] = (__bf16)v.x; r[5] = (__bf16)v.y; r[6] = (__bf16)v.z; r[7] = (__bf16)v.w;
  return r;
}

#define MFMA __builtin_amdgcn_mfma_f32_16x16x32_bf16

// ---------------- prep: bf16 casts + weight fragment-packing ----------------
__global__ __launch_bounds__(256) void prep_kernel(
    const float* __restrict__ hV, const float* __restrict__ W1,
    const float* __restrict__ W2, const float* __restrict__ W3,
    const float* __restrict__ Wi, const float* __restrict__ Wo,
    __bf16* __restrict__ wsb)
{
  int i = blockIdx.x * 256 + threadIdx.x;
  float v;
  if (i < 524288) {
    v = hV[i];
  } else if (i < 589824) {            // W1 pack, src W1[512][128]
    int j = i - 524288;
    int jj = j & 7, ln = (j >> 3) & 63, n = (j >> 9) & 7, ks = j >> 12;
    int k = ks * 32 + (ln >> 4) * 8 + jj, h = n * 16 + (ln & 15);
    v = W1[k * 128 + h];
  } else if (i < 606208) {            // W2 pack, src W2[128][128]
    int j = i - 589824;
    int jj = j & 7, ln = (j >> 3) & 63, n = (j >> 9) & 7, ks = j >> 12;
    int k = ks * 32 + (ln >> 4) * 8 + jj, g = n * 16 + (ln & 15);
    v = W2[k * 128 + g];
  } else if (i < 622592) {            // W3 pack, src W3[128][128]
    int j = i - 606208;
    int jj = j & 7, ln = (j >> 3) & 63, n = (j >> 9) & 7, ks = j >> 12;
    int k = ks * 32 + (ln >> 4) * 8 + jj, h = n * 16 + (ln & 15);
    v = W3[k * 128 + h];
  } else if (i < 688128) {            // Win pack, src Win[128][512]
    int j = i - 622592;
    int jj = j & 7, ln = (j >> 3) & 63, n = (j >> 9) & 31, ks = j >> 14;
    int k = ks * 32 + (ln >> 4) * 8 + jj, o = n * 16 + (ln & 15);
    v = Wi[k * 512 + o];
  } else {                            // Wout pack, src Wout[512][128]
    int j = i - 688128;
    int jj = j & 7, ln = (j >> 3) & 63, n = (j >> 9) & 7, ks = j >> 12;
    int k = ks * 32 + (ln >> 4) * 8 + jj, h = n * 16 + (ln & 15);
    v = Wo[k * 128 + h];
  }
  wsb[i] = (__bf16)v;
}

// ---------------- kernel 1: fused edge MLP + masked K-reduce ----------------
// block = 2 nodes (96 edge rows), 4 waves. Wave w owns output cols
// [w*32, w*32+32) of BOTH nodes -> acc[2][3][2] = 48 VGPRs.
// A (h_EV rows) staged in dbuf LDS tile [96][64] bf16 (12KB x2), XOR-swizzled;
// the same 24KB region is reused as the layer-2/3 activation buffer X.
// B-frags are per-wave coalesced 1KB global loads from packed weights (L2).
__global__ __launch_bounds__(256, 3) void edge_mlp_kernel(
    const float* __restrict__ hE, const float* __restrict__ mask_att,
    const __bf16* __restrict__ wsb,
    const float* __restrict__ b1, const float* __restrict__ b2,
    const float* __restrict__ b3, float* __restrict__ dh)
{
  __shared__ char lds[24576];   // A dbuf (2x12288) == X region (96 rows x 256B)

  const int tid = threadIdx.x;
  const int w = tid >> 6, lane = tid & 63;
  const int lo = lane & 15, hi = lane >> 4;
  const int n0 = blockIdx.x * 2;

  const __bf16* hVb = wsb + OFF_HVB;
  const __bf16* W1p = wsb + OFF_W1P;

  f32x4 acc[2][3][2];
#pragma unroll
  for (int nl = 0; nl < 2; nl++)
#pragma unroll
    for (int m = 0; m < 3; m++)
#pragma unroll
      for (int nn = 0; nn < 2; nn++) {
        acc[nl][m][nn][0] = 0.f; acc[nl][m][nn][1] = 0.f;
        acc[nl][m][nn][2] = 0.f; acc[nl][m][nn][3] = 0.f;
      }

  // Per-thread staging task descriptors: 3 tasks, each = 32B of one hE row.
  const float* tsrc[3];
  int tdst[3];
#pragma unroll
  for (int p = 0; p < 3; p++) {
    int s = p * 256 + tid;          // 0..767
    int row = s >> 3, c8 = s & 7;   // row 0..95, 8 x 32B segments
    int nl = (row >= 48) ? 1 : 0, kk = row - nl * 48;
    tsrc[p] = hE + ((size_t)((n0 + nl) * 48 + kk)) * 384 + c8 * 8;
    tdst[p] = row * 128 + ((c8 * 16) ^ ((row & 7) << 4));
  }

  float4 f1[3], f2[3];
  // ---- prologue: stage chunks 2,3 while computing h_V chunks 0,1 ----
#pragma unroll
  for (int p = 0; p < 3; p++) { f1[p] = *(const float4*)(tsrc[p]); f2[p] = *(const float4*)(tsrc[p] + 4); }

  // compute h_V chunk kc (a-frag identical for all m)
#pragma unroll 1
  for (int kc = 0; kc < 2; ++kc) {
#pragma unroll
    for (int ks32 = 0; ks32 < 2; ++ks32) {
      int ks = kc * 2 + ks32;
      bf16x8 a0 = *(const bf16x8*)(hVb + (n0)     * 128 + ks * 32 + hi * 8);
      bf16x8 a1 = *(const bf16x8*)(hVb + (n0 + 1) * 128 + ks * 32 + hi * 8);
#pragma unroll
      for (int nn = 0; nn < 2; nn++) {
        bf16x8 b = *(const bf16x8*)(W1p + ((ks * 8 + w * 2 + nn) << 9) + lane * 8);
#pragma unroll
        for (int m = 0; m < 3; m++) {
          acc[0][m][nn] = MFMA(a0, b, acc[0][m][nn], 0, 0, 0);
          acc[1][m][nn] = MFMA(a1, b, acc[1][m][nn], 0, 0, 0);
        }
      }
    }
    // write staged chunk kc+2 -> buf[kc], then issue loads for chunk kc+3
#pragma unroll
    for (int p = 0; p < 3; p++)
      *(bf16x8*)(lds + kc * 12288 + tdst[p]) = cvt8(f1[p], f2[p]);
    if (kc == 0) {
#pragma unroll
      for (int p = 0; p < 3; p++) { f1[p] = *(const float4*)(tsrc[p] + 64); f2[p] = *(const float4*)(tsrc[p] + 68); }
    }
  }

  // ---- main loop: chunks 2..7 (hE k = 0..383) ----
#pragma unroll 1
  for (int kc = 2; kc < 8; ++kc) {
    if (kc < 6) {
      const int of = kc * 64;   // loads for chunk kc+2 : hE offset (kc+2-2)*64
#pragma unroll
      for (int p = 0; p < 3; p++) { f1[p] = *(const float4*)(tsrc[p] + of); f2[p] = *(const float4*)(tsrc[p] + of + 4); }
    }
    __syncthreads();   // staged chunk kc visible; compute kc-1 done
    {
      const char* Ab = lds + (kc & 1) * 12288;
#pragma unroll
      for (int ks32 = 0; ks32 < 2; ++ks32) {
        int ks = kc * 2 + ks32;
        bf16x8 bb[2];
#pragma unroll
        for (int nn = 0; nn < 2; nn++)
          bb[nn] = *(const bf16x8*)(W1p + ((ks * 8 + w * 2 + nn) << 9) + lane * 8);
        bf16x8 a[2][3];
#pragma unroll
        for (int nl = 0; nl < 2; nl++)
#pragma unroll
          for (int m = 0; m < 3; m++) {
            int row = nl * 48 + m * 16 + lo;
            a[nl][m] = *(const bf16x8*)(Ab + row * 128 + ((ks32 * 64 + hi * 16) ^ ((row & 7) << 4)));
          }
#pragma unroll
        for (int nn = 0; nn < 2; nn++)
#pragma unroll
          for (int nl = 0; nl < 2; nl++)
#pragma unroll
            for (int m = 0; m < 3; m++)
              acc[nl][m][nn] = MFMA(a[nl][m], bb[nn], acc[nl][m][nn], 0, 0, 0);
      }
    }
    __syncthreads();   // all reads of buf[kc&1] done -> safe to overwrite
    if (kc < 6) {
#pragma unroll
      for (int p = 0; p < 3; p++)
        *(bf16x8*)(lds + (kc & 1) * 12288 + tdst[p]) = cvt8(f1[p], f2[p]);
    }
  }

  // ---- layers 2 and 3: A[96,128] @ W[128,128], X lives in the A region ----
#pragma unroll 1
  for (int layer = 0; layer < 2; ++layer) {
    const float*  bv = layer ? b2 : b1;
    const __bf16* Wp = wsb + (layer ? OFF_W3P : OFF_W2P);
    // gelu(acc + b) -> X [96 rows][256B], swizzled; reset acc
    __syncthreads();   // everyone done reading lds (GEMM1 or previous layer)
#pragma unroll
    for (int nn = 0; nn < 2; nn++) {
      int col = (w * 2 + nn) * 16 + lo;
      float bc = bv[col];
#pragma unroll
      for (int nl = 0; nl < 2; nl++)
#pragma unroll
        for (int m = 0; m < 3; m++)
#pragma unroll
          for (int i = 0; i < 4; i++) {
            int row = nl * 48 + m * 16 + hi * 4 + i;
            float g = gelu_f(acc[nl][m][nn][i] + bc);
            *(__bf16*)(lds + row * 256 + ((col * 2) ^ ((row & 7) << 4))) = (__bf16)g;
            acc[nl][m][nn][i] = 0.f;
          }
    }
    __syncthreads();   // X visible to all waves
#pragma unroll 1
    for (int kc2 = 0; kc2 < 2; ++kc2) {
#pragma unroll
      for (int ks32 = 0; ks32 < 2; ++ks32) {
        int ks = kc2 * 2 + ks32;
        bf16x8 bb[2];
#pragma unroll
        for (int nn = 0; nn < 2; nn++)
          bb[nn] = *(const bf16x8*)(Wp + ((ks * 8 + w * 2 + nn) << 9) + lane * 8);
        bf16x8 a[2][3];
#pragma unroll
        for (int nl = 0; nl < 2; nl++)
#pragma unroll
          for (int m = 0; m < 3; m++) {
            int row = nl * 48 + m * 16 + lo;
            a[nl][m] = *(const bf16x8*)(lds + row * 256 + ((kc2 * 128 + ks32 * 64 + hi * 16) ^ ((row & 7) << 4)));
          }
#pragma unroll
        for (int nn = 0; nn < 2; nn++)
#pragma unroll
          for (int nl = 0; nl < 2; nl++)
#pragma unroll
            for (int m = 0; m < 3; m++)
              acc[nl][m][nn] = MFMA(a[nl][m], bb[nn], acc[nl][m][nn], 0, 0, 0);
      }
    }
  }

  // ---- epilogue: + b3, * mask_attend, sum over 48 rows per node, /SCALE ----
#pragma unroll
  for (int nl = 0; nl < 2; nl++) {
    float msk[12];
#pragma unroll
    for (int m = 0; m < 3; m++)
#pragma unroll
      for (int i = 0; i < 4; i++)
        msk[m * 4 + i] = mask_att[(n0 + nl) * 48 + m * 16 + hi * 4 + i];
#pragma unroll
    for (int nn = 0; nn < 2; nn++) {
      int col = (w * 2 + nn) * 16 + lo;
      float bc = b3[col];
      float s = 0.f;
#pragma unroll
      for (int m = 0; m < 3; m++)
#pragma unroll
        for (int i = 0; i < 4; i++)
          s += (acc[nl][m][nn][i] + bc) * msk[m * 4 + i];
      s += __shfl_xor(s, 16);
      s += __shfl_xor(s, 32);
      if (hi == 0)
        dh[(n0 + nl) * 128 + col] = s * (1.0f / 30.0f);
    }
  }
}

// ---------------- kernel 2: LN1 + FFN + LN2 + mask ----------------
// block = 16 nodes, 4 waves
__global__ __launch_bounds__(256, 2) void node_ffn_kernel(
    const float* __restrict__ hV, const float* __restrict__ maskV,
    const __bf16* __restrict__ wsb, const float* __restrict__ dh,
    const float* __restrict__ Winb, const float* __restrict__ Woutb,
    const float* __restrict__ ns1, const float* __restrict__ no1,
    const float* __restrict__ ns2, const float* __restrict__ no2,
    float* __restrict__ out)
{
  __shared__ char lds2[36864];
  char*  xA  = lds2;                    // [16][256B] bf16, swizzled
  float* hvn = (float*)(lds2 + 4096);   // [16][128] f32
  char*  A2  = lds2 + 12288;            // [16][1024B] bf16, swizzled
  float* red = (float*)(lds2 + 28672);  // [16][128] f32

  const __bf16* Winp  = wsb + OFF_WINP;
  const __bf16* Woutp = wsb + OFF_WOUTP;

  const int tid = threadIdx.x;
  const int w = tid >> 6, lane = tid & 63;
  const int lo = lane & 15, hi = lane >> 4;
  const int n0 = blockIdx.x * 16;

  const int row = tid >> 4;
  const int sg  = tid & 15;
  const int node = n0 + row;

  // Phase 0: x = h_V + dh, LN1 -> hvn (f32) and xA (bf16)
  {
    const float* pv = hV + node * 128 + sg * 8;
    const float* pd = dh + node * 128 + sg * 8;
    float4 a0 = *(const float4*)pv;
    float4 a1 = *(const float4*)(pv + 4);
    float4 d0 = *(const float4*)pd;
    float4 d1 = *(const float4*)(pd + 4);
    float x[8] = { a0.x + d0.x, a0.y + d0.y, a0.z + d0.z, a0.w + d0.w,
                   a1.x + d1.x, a1.y + d1.y, a1.z + d1.z, a1.w + d1.w };
    float s = 0.f, sq = 0.f;
#pragma unroll
    for (int j = 0; j < 8; j++) { s += x[j]; sq += x[j] * x[j]; }
#pragma unroll
    for (int off = 8; off >= 1; off >>= 1) { s += __shfl_xor(s, off); sq += __shfl_xor(sq, off); }
    float mean = s * (1.f / 128.f);
    float var  = sq * (1.f / 128.f) - mean * mean;
    float rs = rsqrtf(var + 1e-5f);
    bf16x8 vb;
    float yv[8];
#pragma unroll
    for (int j = 0; j < 8; j++) {
      int col = sg * 8 + j;
      float y = (x[j] - mean) * rs * ns1[col] + no1[col];
      yv[j] = y; vb[j] = (__bf16)y;
    }
    *(float4*)(hvn + row * 128 + sg * 8)     = make_float4(yv[0], yv[1], yv[2], yv[3]);
    *(float4*)(hvn + row * 128 + sg * 8 + 4) = make_float4(yv[4], yv[5], yv[6], yv[7]);
    *(bf16x8*)(xA + row * 256 + ((sg * 16) ^ ((row & 7) << 4))) = vb;
  }
  __syncthreads();

  // Phase 1: [16,128] @ Win -> [16,512]
  f32x4 acc[8];
#pragma unroll
  for (int n = 0; n < 8; n++) { acc[n][0] = 0.f; acc[n][1] = 0.f; acc[n][2] = 0.f; acc[n][3] = 0.f; }
#pragma unroll
  for (int ks = 0; ks < 4; ks++) {
    const int kb = (ks * 32 + hi * 8) * 2;
    bf16x8 a = *(const bf16x8*)(xA + lo * 256 + (kb ^ ((lo & 7) << 4)));
#pragma unroll
    for (int n = 0; n < 8; n++) {
      int ng = w * 8 + n;
      bf16x8 b = *(const bf16x8*)(Winp + ((ks * 32 + ng) << 9) + lane * 8);
      acc[n] = MFMA(a, b, acc[n], 0, 0, 0);
    }
  }
  // Phase 2: gelu -> A2
#pragma unroll
  for (int n = 0; n < 8; n++) {
    int col = w * 128 + n * 16 + lo;
    float bc = Winb[col];
#pragma unroll
    for (int i = 0; i < 4; i++) {
      int r2 = hi * 4 + i;
      float g = gelu_f(acc[n][i] + bc);
      *(__bf16*)(A2 + r2 * 1024 + ((col * 2) ^ ((r2 & 7) << 4))) = (__bf16)g;
    }
  }
  __syncthreads();

  // Phase 3: [16,512] @ Wout -> [16,128]
  f32x4 acc2[2];
  acc2[0][0] = 0.f; acc2[0][1] = 0.f; acc2[0][2] = 0.f; acc2[0][3] = 0.f;
  acc2[1][0] = 0.f; acc2[1][1] = 0.f; acc2[1][2] = 0.f; acc2[1][3] = 0.f;
#pragma unroll
  for (int ks = 0; ks < 16; ks++) {
    const int kb = (ks * 32 + hi * 8) * 2;
    bf16x8 a = *(const bf16x8*)(A2 + lo * 1024 + (kb ^ ((lo & 7) << 4)));
#pragma unroll
    for (int n = 0; n < 2; n++) {
      int ng = w * 2 + n;
      bf16x8 b = *(const bf16x8*)(Woutp + ((ks * 8 + ng) << 9) + lane * 8);
      acc2[n] = MFMA(a, b, acc2[n], 0, 0, 0);
    }
  }
  // Phase 4: + bias -> red
#pragma unroll
  for (int n = 0; n < 2; n++) {
    int col = w * 32 + n * 16 + lo;
    float bc = Woutb[col];
#pragma unroll
    for (int i = 0; i < 4; i++) {
      int r2 = hi * 4 + i;
      red[r2 * 128 + col] = acc2[n][i] + bc;
    }
  }
  __syncthreads();

  // Phase 5: LN2(hvn + red) * mask_V -> out
  {
    const float* ph = hvn + row * 128 + sg * 8;
    const float* pr = red + row * 128 + sg * 8;
    float4 h0 = *(const float4*)ph;
    float4 h1 = *(const float4*)(ph + 4);
    float4 r0 = *(const float4*)pr;
    float4 r1 = *(const float4*)(pr + 4);
    float x[8] = { h0.x + r0.x, h0.y + r0.y, h0.z + r0.z, h0.w + r0.w,
                   h1.x + r1.x, h1.y + r1.y, h1.z + r1.z, h1.w + r1.w };
    float s = 0.f, sq = 0.f;
#pragma unroll
    for (int j = 0; j < 8; j++) { s += x[j]; sq += x[j] * x[j]; }
#pragma unroll
    for (int off = 8; off >= 1; off >>= 1) { s += __shfl_xor(s, off); sq += __shfl_xor(sq, off); }
    float mean = s * (1.f / 128.f);
    float var  = sq * (1.f / 128.f) - mean * mean;
    float rs = rsqrtf(var + 1e-5f);
    float mv = maskV[node];
    float o[8];
#pragma unroll
    for (int j = 0; j < 8; j++) {
      int col = sg * 8 + j;
      o[j] = mv * ((x[j] - mean) * rs * ns2[col] + no2[col]);
    }
    *(float4*)(out + node * 128 + sg * 8)     = make_float4(o[0], o[1], o[2], o[3]);
    *(float4*)(out + node * 128 + sg * 8 + 4) = make_float4(o[4], o[5], o[6], o[7]);
  }
}

extern "C" void kernel_launch(void* const* d_in, const int* in_sizes, int n_in,
                              void* d_out, int out_size, void* d_ws, size_t ws_size,
                              hipStream_t stream)
{
  (void)in_sizes; (void)n_in; (void)out_size; (void)ws_size;
  const float* hV   = (const float*)d_in[0];
  const float* hE   = (const float*)d_in[1];
  const float* mV   = (const float*)d_in[2];
  const float* mAtt = (const float*)d_in[3];
  const float* W1   = (const float*)d_in[4];
  const float* b1   = (const float*)d_in[5];
  const float* W2   = (const float*)d_in[6];
  const float* b2   = (const float*)d_in[7];
  const float* W3   = (const float*)d_in[8];
  const float* b3   = (const float*)d_in[9];
  const float* Win  = (const float*)d_in[10];
  const float* binb = (const float*)d_in[11];
  const float* Wout = (const float*)d_in[12];
  const float* bout = (const float*)d_in[13];
  const float* ns1  = (const float*)d_in[14];
  const float* no1  = (const float*)d_in[15];
  const float* ns2  = (const float*)d_in[16];
  const float* no2  = (const float*)d_in[17];

  __bf16* wsb = (__bf16*)d_ws;
  float* dh   = (float*)((char*)d_ws + OFF_DH_BYTES);
  float* out  = (float*)d_out;

  prep_kernel<<<NPREP / 256, 256, 0, stream>>>(hV, W1, W2, W3, Win, Wout, wsb);
  edge_mlp_kernel<<<2048, 256, 0, stream>>>(hE, mAtt, wsb, b1, b2, b3, dh);
  node_ffn_kernel<<<256, 256, 0, stream>>>(hV, mV, wsb, dh, binb, bout,
                                           ns1, no1, ns2, no2, out);
}